// Round 5
// baseline (266.895 us; speedup 1.0000x reference)
//
#include <hip/hip_runtime.h>
#include <hip/hip_cooperative_groups.h>
#include <math.h>

namespace cg = cooperative_groups;

__device__ __forceinline__ float silu(float x){ return x / (1.f + expf(-x)); }

// Single fused cooperative kernel. 256 blocks x 256 threads.
// Phase A: input GEMVs (12352 rows, 2 rows/wave, grid-strided)
// Phase B: blocks 0..31 conv+state+RMSnorm; ALL blocks then L2-warm their own
//          8 W_out rows (same block consumes them in phase C -> same-XCD L2 hit)
// Phase C: output GEMV (8 rows/block)
__global__ __launch_bounds__(256) void k_fused(
    const float* __restrict__ x,
    const float* __restrict__ conv_state,
    const float* __restrict__ W_qkv,
    const float* __restrict__ W_z,
    const float* __restrict__ W_b,
    const float* __restrict__ W_a,
    const float* __restrict__ conv_w,
    const float* __restrict__ A_log,
    const float* __restrict__ dt_bias,
    const float* __restrict__ norm_w,
    const float* __restrict__ state,
    const float* __restrict__ Wout,
    float* __restrict__ out,          // 2048
    float* __restrict__ new_state,    // 524288
    float* __restrict__ new_conv,     // 24576
    float* __restrict__ mixed,        // ws 8192
    float* __restrict__ zb,           // ws 4096
    float* __restrict__ b_raw,        // ws 32
    float* __restrict__ a_raw,        // ws 32
    float* __restrict__ oflat,        // ws 4096
    float* __restrict__ scratch)      // ws 256
{
  cg::grid_group grid = cg::this_grid();
  const int b    = blockIdx.x;
  const int tid  = threadIdx.x;
  const int lane = tid & 63;
  const int wave = tid >> 6;

  __shared__ float qn[128], kn[128];
  __shared__ __align__(16) float vs[128];
  __shared__ float4 kvp[8][32];
  __shared__ float red[4];
  __shared__ __align__(16) float xs[4096];

  // ================= Phase A: input GEMVs =================
  {
    float4 xr[8];
    #pragma unroll
    for (int j = 0; j < 8; j++)
      xr[j] = *(const float4*)(x + j*256 + lane*4);

    for (int row0 = (b*4 + wave)*2; row0 < 12352; row0 += 2048){
      const float* W; float* dst;
      if (row0 < 8192)       { W = W_qkv + (size_t)row0 * 2048;          dst = mixed + row0; }
      else if (row0 < 12288) { W = W_z   + (size_t)(row0-8192) * 2048;   dst = zb + (row0-8192); }
      else if (row0 < 12320) { W = W_b   + (size_t)(row0-12288) * 2048;  dst = b_raw + (row0-12288); }
      else                   { W = W_a   + (size_t)(row0-12320) * 2048;  dst = a_raw + (row0-12320); }

      float acc0 = 0.f, acc1 = 0.f;
      #pragma unroll
      for (int j = 0; j < 8; j++){
        float4 w0 = *(const float4*)(W + j*256 + lane*4);
        float4 w1 = *(const float4*)(W + 2048 + j*256 + lane*4);
        acc0 += w0.x*xr[j].x + w0.y*xr[j].y + w0.z*xr[j].z + w0.w*xr[j].w;
        acc1 += w1.x*xr[j].x + w1.y*xr[j].y + w1.z*xr[j].z + w1.w*xr[j].w;
      }
      #pragma unroll
      for (int off = 32; off >= 1; off >>= 1){
        acc0 += __shfl_xor(acc0, off, 64);
        acc1 += __shfl_xor(acc1, off, 64);
      }
      if (lane == 0){ dst[0] = acc0; dst[1] = acc1; }
    }
  }

  grid.sync();

  // ================= Phase B: head update (blocks 0..31) =================
  if (b < 32){
    const int h  = b;
    const int hb = h >> 1;
    const int t  = tid & 127;
    const int wid = tid >> 6;

    // conv + silu (threads 0..127: q,k ; threads 128..255: v)
    float qv = 0.f, kv = 0.f;
    if (tid < 128){
      int c = hb*128 + t;
      float c0 = conv_state[c*3+0], c1 = conv_state[c*3+1], c2 = conv_state[c*3+2];
      float m  = mixed[c];
      qv = silu(c0*conv_w[c*4+0] + c1*conv_w[c*4+1] + c2*conv_w[c*4+2] + m*conv_w[c*4+3]);
      new_conv[c*3+0] = c1; new_conv[c*3+1] = c2; new_conv[c*3+2] = m;
      c = 2048 + hb*128 + t;
      c0 = conv_state[c*3+0]; c1 = conv_state[c*3+1]; c2 = conv_state[c*3+2];
      m  = mixed[c];
      kv = silu(c0*conv_w[c*4+0] + c1*conv_w[c*4+1] + c2*conv_w[c*4+2] + m*conv_w[c*4+3]);
      new_conv[c*3+0] = c1; new_conv[c*3+1] = c2; new_conv[c*3+2] = m;

      float sq = qv*qv, sk = kv*kv;
      #pragma unroll
      for (int off = 32; off >= 1; off >>= 1){
        sq += __shfl_xor(sq, off, 64);
        sk += __shfl_xor(sk, off, 64);
      }
      if (lane == 0){ red[wid] = sq; red[2+wid] = sk; }
    } else {
      int c = 4096 + h*128 + t;
      float c0 = conv_state[c*3+0], c1 = conv_state[c*3+1], c2 = conv_state[c*3+2];
      float m  = mixed[c];
      vs[t] = silu(c0*conv_w[c*4+0] + c1*conv_w[c*4+1] + c2*conv_w[c*4+2] + m*conv_w[c*4+3]);
      new_conv[c*3+0] = c1; new_conv[c*3+1] = c2; new_conv[c*3+2] = m;
    }
    __syncthreads();
    const float qscale = rsqrtf(red[0]+red[1] + 1e-6f) * 0.088388347648318440550f; // 1/sqrt(128)
    const float kscale = rsqrtf(red[2]+red[3] + 1e-6f);
    if (tid < 128){ qn[t] = qv * qscale; kn[t] = kv * kscale; }
    __syncthreads();

    float g_t, beta;
    {
      const float av = a_raw[h] + dt_bias[h];
      const float sp = (av > 20.f) ? av : log1pf(expf(av));   // softplus
      g_t  = expf(-expf(A_log[h]) * sp);
      beta = 1.f / (1.f + expf(-b_raw[h]));
    }

    // state update: rows k0..k0+15, cols 4*cg..4*cg+3
    const int cg_ = tid & 31, part = tid >> 5;
    const int k0 = part * 16;
    const float* st  = state     + (size_t)h * 16384;
    float*       nst = new_state + (size_t)h * 16384;

    float4 s4[16];
    float4 kvm = make_float4(0.f, 0.f, 0.f, 0.f);
    #pragma unroll
    for (int i = 0; i < 16; i++){
      float4 sv = *(const float4*)(st + (k0+i)*128 + cg_*4);
      sv.x *= g_t; sv.y *= g_t; sv.z *= g_t; sv.w *= g_t;
      s4[i] = sv;
      const float kk = kn[k0+i];
      kvm.x += sv.x*kk; kvm.y += sv.y*kk; kvm.z += sv.z*kk; kvm.w += sv.w*kk;
    }
    kvp[part][cg_] = kvm;
    __syncthreads();
    float4 kt = make_float4(0.f, 0.f, 0.f, 0.f);
    #pragma unroll
    for (int p = 0; p < 8; p++){
      float4 kp = kvp[p][cg_];
      kt.x += kp.x; kt.y += kp.y; kt.z += kp.z; kt.w += kp.w;
    }
    const float4 v4 = *(const float4*)(vs + cg_*4);
    float4 delta;
    delta.x = (v4.x - kt.x) * beta;
    delta.y = (v4.y - kt.y) * beta;
    delta.z = (v4.z - kt.z) * beta;
    delta.w = (v4.w - kt.w) * beta;

    float4 oacc = make_float4(0.f, 0.f, 0.f, 0.f);
    #pragma unroll
    for (int i = 0; i < 16; i++){
      const float kk = kn[k0+i];
      float4 ns;
      ns.x = s4[i].x + kk*delta.x;
      ns.y = s4[i].y + kk*delta.y;
      ns.z = s4[i].z + kk*delta.z;
      ns.w = s4[i].w + kk*delta.w;
      *(float4*)(nst + (k0+i)*128 + cg_*4) = ns;
      const float qq = qn[k0+i];
      oacc.x += ns.x*qq; oacc.y += ns.y*qq; oacc.z += ns.z*qq; oacc.w += ns.w*qq;
    }
    __syncthreads();           // kvp reuse
    kvp[part][cg_] = oacc;
    __syncthreads();
    if (part == 0){
      float4 o = make_float4(0.f, 0.f, 0.f, 0.f);
      #pragma unroll
      for (int p = 0; p < 8; p++){
        float4 op = kvp[p][cg_];
        o.x += op.x; o.y += op.y; o.z += op.z; o.w += op.w;
      }
      const float4 z4 = *(const float4*)(zb + h*128 + cg_*4);
      float4 g4;
      g4.x = o.x * silu(z4.x);
      g4.y = o.y * silu(z4.y);
      g4.z = o.z * silu(z4.z);
      g4.w = o.w * silu(z4.w);
      float s2 = g4.x*g4.x + g4.y*g4.y + g4.z*g4.z + g4.w*g4.w;
      #pragma unroll
      for (int off = 16; off >= 1; off >>= 1) s2 += __shfl_xor(s2, off, 64);
      const float r = rsqrtf(s2 * (1.f/128.f) + 1e-6f);
      const float4 nw = *(const float4*)(norm_w + cg_*4);
      float4 ov;
      ov.x = g4.x * r * nw.x;
      ov.y = g4.y * r * nw.y;
      ov.z = g4.z * r * nw.z;
      ov.w = g4.w * r * nw.w;
      *(float4*)(oflat + h*128 + cg_*4) = ov;
    }
  }

  // ---- All blocks: L2-warm our own W_out rows [b*8, b*8+8) for phase C ----
  {
    const float4* W4 = (const float4*)Wout + (size_t)b * 8192;
    float4 a = make_float4(0.f, 0.f, 0.f, 0.f);
    #pragma unroll
    for (int j = 0; j < 32; j++){
      float4 w = W4[j*256 + tid];
      a.x += w.x; a.y += w.y; a.z += w.z; a.w += w.w;
    }
    if (tid == 0) scratch[b] = a.x + a.y + a.z + a.w;  // keep loads live
  }

  grid.sync();

  // ================= Phase C: output GEMV (8 rows/block) =================
  {
    #pragma unroll
    for (int i = 0; i < 4; i++)
      *(float4*)(xs + tid*4 + i*1024) = *(const float4*)(oflat + tid*4 + i*1024);
    __syncthreads();

    const int row0 = b * 8 + wave * 2;
    const float* W0 = Wout + (size_t)row0 * 4096;
    float acc0 = 0.f, acc1 = 0.f;
    #pragma unroll
    for (int j = 0; j < 16; j++){
      float4 w0 = *(const float4*)(W0 + j*256 + lane*4);
      float4 w1 = *(const float4*)(W0 + 4096 + j*256 + lane*4);
      const float x0 = xs[j*256+lane*4+0], x1 = xs[j*256+lane*4+1];
      const float x2 = xs[j*256+lane*4+2], x3 = xs[j*256+lane*4+3];
      acc0 += w0.x*x0 + w0.y*x1 + w0.z*x2 + w0.w*x3;
      acc1 += w1.x*x0 + w1.y*x1 + w1.z*x2 + w1.w*x3;
    }
    #pragma unroll
    for (int off = 32; off >= 1; off >>= 1){
      acc0 += __shfl_xor(acc0, off, 64);
      acc1 += __shfl_xor(acc1, off, 64);
    }
    if (lane == 0){ out[row0] = acc0; out[row0+1] = acc1; }
  }
}

extern "C" void kernel_launch(void* const* d_in, const int* in_sizes, int n_in,
                              void* d_out, int out_size, void* d_ws, size_t ws_size,
                              hipStream_t stream) {
  const float* x          = (const float*)d_in[0];
  const float* state      = (const float*)d_in[1];
  const float* conv_state = (const float*)d_in[2];
  const float* W_qkv      = (const float*)d_in[3];
  const float* W_z        = (const float*)d_in[4];
  const float* W_b        = (const float*)d_in[5];
  const float* W_a        = (const float*)d_in[6];
  const float* conv_w     = (const float*)d_in[7];
  const float* A_log      = (const float*)d_in[8];
  const float* dt_bias    = (const float*)d_in[9];
  const float* norm_w     = (const float*)d_in[10];
  const float* W_out      = (const float*)d_in[11];

  float* out       = (float*)d_out;                 // 2048
  float* new_state = (float*)d_out + 2048;          // 524288
  float* new_conv  = (float*)d_out + 2048 + 524288; // 24576

  float* ws      = (float*)d_ws;
  float* mixed   = ws;          // 8192
  float* zb      = ws + 8192;   // 4096
  float* b_raw   = ws + 12288;  // 32
  float* a_raw   = ws + 12320;  // 32
  float* oflat   = ws + 12352;  // 4096
  float* scratch = ws + 16448;  // 256

  void* args[] = {
    (void*)&x, (void*)&conv_state, (void*)&W_qkv, (void*)&W_z, (void*)&W_b,
    (void*)&W_a, (void*)&conv_w, (void*)&A_log, (void*)&dt_bias, (void*)&norm_w,
    (void*)&state, (void*)&W_out,
    (void*)&out, (void*)&new_state, (void*)&new_conv,
    (void*)&mixed, (void*)&zb, (void*)&b_raw, (void*)&a_raw, (void*)&oflat,
    (void*)&scratch
  };
  hipLaunchCooperativeKernel((const void*)k_fused, dim3(256), dim3(256),
                             args, 0, stream);
}

// Round 6
// 179.471 us; speedup vs baseline: 1.4871x; 1.4871x over previous
//
#include <hip/hip_runtime.h>
#include <hip/hip_cooperative_groups.h>
#include <math.h>

namespace cg = cooperative_groups;

__device__ __forceinline__ float silu(float x){ return x / (1.f + expf(-x)); }

// ---------- shared: input GEMV over row-pairs (grid-stride) ----------
// rows 0..8191 -> mixed, 8192..12287 -> z, 12288..12319 -> b_raw, 12320..12351 -> a_raw
__device__ __forceinline__ void gemv_in_pairs(
    int pairIdx, int pairStride, int lane,
    const float* __restrict__ x,
    const float* __restrict__ W_qkv, const float* __restrict__ W_z,
    const float* __restrict__ W_b,   const float* __restrict__ W_a,
    float* __restrict__ mixed, float* __restrict__ zb,
    float* __restrict__ b_raw, float* __restrict__ a_raw)
{
  float4 xr[8];
  #pragma unroll
  for (int j = 0; j < 8; j++)
    xr[j] = *(const float4*)(x + j*256 + lane*4);

  for (int rp = pairIdx; rp < 6176; rp += pairStride){
    const int row0 = rp * 2;            // even; pair never straddles a segment
    const float* W; float* dst;
    if (row0 < 8192)       { W = W_qkv + (size_t)row0 * 2048;          dst = mixed + row0; }
    else if (row0 < 12288) { W = W_z   + (size_t)(row0-8192) * 2048;   dst = zb + (row0-8192); }
    else if (row0 < 12320) { W = W_b   + (size_t)(row0-12288) * 2048;  dst = b_raw + (row0-12288); }
    else                   { W = W_a   + (size_t)(row0-12320) * 2048;  dst = a_raw + (row0-12320); }

    float acc0 = 0.f, acc1 = 0.f;
    #pragma unroll
    for (int j = 0; j < 8; j++){
      float4 w0 = *(const float4*)(W + j*256 + lane*4);
      float4 w1 = *(const float4*)(W + 2048 + j*256 + lane*4);
      acc0 += w0.x*xr[j].x + w0.y*xr[j].y + w0.z*xr[j].z + w0.w*xr[j].w;
      acc1 += w1.x*xr[j].x + w1.y*xr[j].y + w1.z*xr[j].z + w1.w*xr[j].w;
    }
    #pragma unroll
    for (int off = 32; off >= 1; off >>= 1){
      acc0 += __shfl_xor(acc0, off, 64);
      acc1 += __shfl_xor(acc1, off, 64);
    }
    if (lane == 0){ dst[0] = acc0; dst[1] = acc1; }
  }
}

// ---------- shared: per-head conv+silu + state update + gated RMSnorm ----------
struct HeadSmem {
  float qn[128];
  float kn[128];
  __align__(16) float vs[128];
  float4 kvp[8][32];
  float red[4];
};

__device__ __forceinline__ void head_work(
    int h, int tid, HeadSmem& sm,
    const float* __restrict__ mixed,      const float* __restrict__ conv_state,
    const float* __restrict__ conv_w,     const float* __restrict__ zbuf,
    const float* __restrict__ b_raw,      const float* __restrict__ a_raw,
    const float* __restrict__ A_log,      const float* __restrict__ dt_bias,
    const float* __restrict__ norm_w,     const float* __restrict__ state,
    float* __restrict__ new_state, float* __restrict__ new_conv,
    float* __restrict__ out_flat)
{
  const int hb = h >> 1;
  const int t  = tid & 127;
  const int lane = tid & 63, wid = tid >> 6;

  // conv + silu (threads 0..127: q,k ; threads 128..255: v)
  float qv = 0.f, kv = 0.f;
  if (tid < 128){
    int c = hb*128 + t;
    float c0 = conv_state[c*3+0], c1 = conv_state[c*3+1], c2 = conv_state[c*3+2];
    float m  = mixed[c];
    qv = silu(c0*conv_w[c*4+0] + c1*conv_w[c*4+1] + c2*conv_w[c*4+2] + m*conv_w[c*4+3]);
    new_conv[c*3+0] = c1; new_conv[c*3+1] = c2; new_conv[c*3+2] = m;
    c = 2048 + hb*128 + t;
    c0 = conv_state[c*3+0]; c1 = conv_state[c*3+1]; c2 = conv_state[c*3+2];
    m  = mixed[c];
    kv = silu(c0*conv_w[c*4+0] + c1*conv_w[c*4+1] + c2*conv_w[c*4+2] + m*conv_w[c*4+3]);
    new_conv[c*3+0] = c1; new_conv[c*3+1] = c2; new_conv[c*3+2] = m;

    float sq = qv*qv, sk = kv*kv;
    #pragma unroll
    for (int off = 32; off >= 1; off >>= 1){
      sq += __shfl_xor(sq, off, 64);
      sk += __shfl_xor(sk, off, 64);
    }
    if (lane == 0){ sm.red[wid] = sq; sm.red[2+wid] = sk; }
  } else {
    int c = 4096 + h*128 + t;
    float c0 = conv_state[c*3+0], c1 = conv_state[c*3+1], c2 = conv_state[c*3+2];
    float m  = mixed[c];
    sm.vs[t] = silu(c0*conv_w[c*4+0] + c1*conv_w[c*4+1] + c2*conv_w[c*4+2] + m*conv_w[c*4+3]);
    new_conv[c*3+0] = c1; new_conv[c*3+1] = c2; new_conv[c*3+2] = m;
  }
  __syncthreads();
  const float qscale = rsqrtf(sm.red[0]+sm.red[1] + 1e-6f) * 0.088388347648318440550f; // 1/sqrt(128)
  const float kscale = rsqrtf(sm.red[2]+sm.red[3] + 1e-6f);
  if (tid < 128){ sm.qn[t] = qv * qscale; sm.kn[t] = kv * kscale; }
  __syncthreads();

  float g_t, beta;
  {
    const float av = a_raw[h] + dt_bias[h];
    const float sp = (av > 20.f) ? av : log1pf(expf(av));   // softplus
    g_t  = expf(-expf(A_log[h]) * sp);
    beta = 1.f / (1.f + expf(-b_raw[h]));
  }

  // state update: rows k0..k0+15, cols 4*cg..4*cg+3
  const int cg_ = tid & 31, part = tid >> 5;
  const int k0 = part * 16;
  const float* st  = state     + (size_t)h * 16384;
  float*       nst = new_state + (size_t)h * 16384;

  float4 s4[16];
  float4 kvm = make_float4(0.f, 0.f, 0.f, 0.f);
  #pragma unroll
  for (int i = 0; i < 16; i++){
    float4 sv = *(const float4*)(st + (k0+i)*128 + cg_*4);
    sv.x *= g_t; sv.y *= g_t; sv.z *= g_t; sv.w *= g_t;
    s4[i] = sv;
    const float kk = sm.kn[k0+i];
    kvm.x += sv.x*kk; kvm.y += sv.y*kk; kvm.z += sv.z*kk; kvm.w += sv.w*kk;
  }
  sm.kvp[part][cg_] = kvm;
  __syncthreads();
  float4 kt = make_float4(0.f, 0.f, 0.f, 0.f);
  #pragma unroll
  for (int p = 0; p < 8; p++){
    float4 kp = sm.kvp[p][cg_];
    kt.x += kp.x; kt.y += kp.y; kt.z += kp.z; kt.w += kp.w;
  }
  const float4 v4 = *(const float4*)(sm.vs + cg_*4);
  float4 delta;
  delta.x = (v4.x - kt.x) * beta;
  delta.y = (v4.y - kt.y) * beta;
  delta.z = (v4.z - kt.z) * beta;
  delta.w = (v4.w - kt.w) * beta;

  float4 oacc = make_float4(0.f, 0.f, 0.f, 0.f);
  #pragma unroll
  for (int i = 0; i < 16; i++){
    const float kk = sm.kn[k0+i];
    float4 ns;
    ns.x = s4[i].x + kk*delta.x;
    ns.y = s4[i].y + kk*delta.y;
    ns.z = s4[i].z + kk*delta.z;
    ns.w = s4[i].w + kk*delta.w;
    *(float4*)(nst + (k0+i)*128 + cg_*4) = ns;
    const float qq = sm.qn[k0+i];
    oacc.x += ns.x*qq; oacc.y += ns.y*qq; oacc.z += ns.z*qq; oacc.w += ns.w*qq;
  }
  __syncthreads();           // kvp reuse
  sm.kvp[part][cg_] = oacc;
  __syncthreads();
  if (part == 0){
    float4 o = make_float4(0.f, 0.f, 0.f, 0.f);
    #pragma unroll
    for (int p = 0; p < 8; p++){
      float4 op = sm.kvp[p][cg_];
      o.x += op.x; o.y += op.y; o.z += op.z; o.w += op.w;
    }
    const float4 z4 = *(const float4*)(zbuf + h*128 + cg_*4);
    float4 g4;
    g4.x = o.x * silu(z4.x);
    g4.y = o.y * silu(z4.y);
    g4.z = o.z * silu(z4.z);
    g4.w = o.w * silu(z4.w);
    float s2 = g4.x*g4.x + g4.y*g4.y + g4.z*g4.z + g4.w*g4.w;
    #pragma unroll
    for (int off = 16; off >= 1; off >>= 1) s2 += __shfl_xor(s2, off, 64);
    const float r = rsqrtf(s2 * (1.f/128.f) + 1e-6f);
    const float4 nw = *(const float4*)(norm_w + cg_*4);
    float4 ov;
    ov.x = g4.x * r * nw.x;
    ov.y = g4.y * r * nw.y;
    ov.z = g4.z * r * nw.z;
    ov.w = g4.w * r * nw.w;
    *(float4*)(out_flat + h*128 + cg_*4) = ov;
  }
}

// ================= Fused cooperative kernel: 1024 blocks x 256 thr =================
// __launch_bounds__(256,4): 4 waves/EU = 16 waves/CU = 4 blocks/CU co-resident.
__global__ __launch_bounds__(256, 4) void k_fused(
    const float* __restrict__ x,
    const float* __restrict__ conv_state,
    const float* __restrict__ W_qkv,
    const float* __restrict__ W_z,
    const float* __restrict__ W_b,
    const float* __restrict__ W_a,
    const float* __restrict__ conv_w,
    const float* __restrict__ A_log,
    const float* __restrict__ dt_bias,
    const float* __restrict__ norm_w,
    const float* __restrict__ state,
    const float* __restrict__ Wout,
    float* __restrict__ out,
    float* __restrict__ new_state,
    float* __restrict__ new_conv,
    float* __restrict__ mixed,
    float* __restrict__ zb,
    float* __restrict__ b_raw,
    float* __restrict__ a_raw,
    float* __restrict__ oflat,
    float* __restrict__ scratch)
{
  cg::grid_group grid = cg::this_grid();
  const int b    = blockIdx.x;
  const int tid  = threadIdx.x;
  const int lane = tid & 63;
  const int wave = tid >> 6;

  __shared__ HeadSmem sm;
  __shared__ __align__(16) float xs[4096];
  __shared__ float redC[4];

  // Phase A: 6176 row-pairs over 4096 waves
  gemv_in_pairs(b*4 + wave, 4096, lane, x, W_qkv, W_z, W_b, W_a,
                mixed, zb, b_raw, a_raw);

  grid.sync();

  // Phase B
  if (b < 32){
    head_work(b, tid, sm, mixed, conv_state, conv_w, zb, b_raw, a_raw,
              A_log, dt_bias, norm_w, state, new_state, new_conv, oflat);
  } else {
    // L2-warm our own W_out rows [2b, 2b+2) (consumed by this block in phase C)
    const float4* W4 = (const float4*)Wout + (size_t)b * 2048;
    float4 a = make_float4(0.f, 0.f, 0.f, 0.f);
    #pragma unroll
    for (int j = 0; j < 8; j++){
      float4 w = W4[j*256 + tid];
      a.x += w.x; a.y += w.y; a.z += w.z; a.w += w.w;
    }
    if (b >= 992){   // cover head-blocks' rows [2(b-992), 2(b-992)+2)
      const float4* W2 = (const float4*)Wout + (size_t)(b-992) * 2048;
      #pragma unroll
      for (int j = 0; j < 8; j++){
        float4 w = W2[j*256 + tid];
        a.x += w.x; a.y += w.y; a.z += w.z; a.w += w.w;
      }
    }
    if (tid == 0) scratch[b] = a.x + a.y + a.z + a.w;  // keep loads live
  }

  grid.sync();

  // Phase C: 2 rows/block; wave pair per row, half-row per wave
  #pragma unroll
  for (int i = 0; i < 4; i++)
    *(float4*)(xs + tid*4 + i*1024) = *(const float4*)(oflat + tid*4 + i*1024);
  __syncthreads();

  const int row  = b*2 + (wave >> 1);
  const int half = wave & 1;
  const float* Wr = Wout + (size_t)row * 4096 + half * 2048;
  const float* xh = xs + half * 2048;
  float acc = 0.f;
  #pragma unroll
  for (int j = 0; j < 8; j++){
    float4 w = *(const float4*)(Wr + j*256 + lane*4);
    acc += w.x*xh[j*256+lane*4+0] + w.y*xh[j*256+lane*4+1]
         + w.z*xh[j*256+lane*4+2] + w.w*xh[j*256+lane*4+3];
  }
  #pragma unroll
  for (int off = 32; off >= 1; off >>= 1) acc += __shfl_xor(acc, off, 64);
  if (lane == 0) redC[wave] = acc;
  __syncthreads();
  if (tid < 2) out[b*2 + tid] = redC[2*tid] + redC[2*tid+1];
}

// ================= Fallback path (R4 3-kernel structure) =================
__global__ __launch_bounds__(256) void k_gemv_in(
    const float* __restrict__ x,
    const float* __restrict__ W_qkv, const float* __restrict__ W_z,
    const float* __restrict__ W_b,   const float* __restrict__ W_a,
    float* __restrict__ mixed, float* __restrict__ zb,
    float* __restrict__ b_raw, float* __restrict__ a_raw)
{
  const int lane = threadIdx.x & 63, wave = threadIdx.x >> 6;
  gemv_in_pairs(blockIdx.x*4 + wave, 6176, lane, x, W_qkv, W_z, W_b, W_a,
                mixed, zb, b_raw, a_raw);
}

__global__ __launch_bounds__(256) void k_head(
    const float* __restrict__ mixed,      const float* __restrict__ conv_state,
    const float* __restrict__ conv_w,     const float* __restrict__ zbuf,
    const float* __restrict__ b_raw,      const float* __restrict__ a_raw,
    const float* __restrict__ A_log,      const float* __restrict__ dt_bias,
    const float* __restrict__ norm_w,     const float* __restrict__ state,
    const float* __restrict__ Wout,
    float* __restrict__ new_state, float* __restrict__ new_conv,
    float* __restrict__ out_flat,  float* __restrict__ scratch)
{
  const int b = blockIdx.x, tid = threadIdx.x;
  if (b >= 32){
    const float4* W4 = (const float4*)Wout + (size_t)b * 8192;
    float4 a = make_float4(0.f, 0.f, 0.f, 0.f);
    #pragma unroll
    for (int j = 0; j < 32; j++){
      float4 w = W4[j*256 + tid];
      a.x += w.x; a.y += w.y; a.z += w.z; a.w += w.w;
    }
    if (tid == 0) scratch[b] = a.x + a.y + a.z + a.w;
    return;
  }
  __shared__ HeadSmem sm;
  head_work(b, tid, sm, mixed, conv_state, conv_w, zbuf, b_raw, a_raw,
            A_log, dt_bias, norm_w, state, new_state, new_conv, out_flat);
}

__global__ __launch_bounds__(256) void k_gemv_out(
    const float* __restrict__ out_flat,
    const float* __restrict__ Wout,
    float* __restrict__ out)
{
  __shared__ __align__(16) float xs[4096];
  const int tid = threadIdx.x;
  #pragma unroll
  for (int i = 0; i < 4; i++)
    *(float4*)(xs + tid*4 + i*1024) = *(const float4*)(out_flat + tid*4 + i*1024);
  __syncthreads();

  const int lane = tid & 63, wave = tid >> 6;
  const int row0 = blockIdx.x * 8 + wave * 2;
  const float* W0 = Wout + (size_t)row0 * 4096;
  float acc0 = 0.f, acc1 = 0.f;
  #pragma unroll
  for (int j = 0; j < 16; j++){
    float4 w0 = *(const float4*)(W0 + j*256 + lane*4);
    float4 w1 = *(const float4*)(W0 + 4096 + j*256 + lane*4);
    const float x0 = xs[j*256+lane*4+0], x1 = xs[j*256+lane*4+1];
    const float x2 = xs[j*256+lane*4+2], x3 = xs[j*256+lane*4+3];
    acc0 += w0.x*x0 + w0.y*x1 + w0.z*x2 + w0.w*x3;
    acc1 += w1.x*x0 + w1.y*x1 + w1.z*x2 + w1.w*x3;
  }
  #pragma unroll
  for (int off = 32; off >= 1; off >>= 1){
    acc0 += __shfl_xor(acc0, off, 64);
    acc1 += __shfl_xor(acc1, off, 64);
  }
  if (lane == 0){ out[row0] = acc0; out[row0+1] = acc1; }
}

extern "C" void kernel_launch(void* const* d_in, const int* in_sizes, int n_in,
                              void* d_out, int out_size, void* d_ws, size_t ws_size,
                              hipStream_t stream) {
  const float* x          = (const float*)d_in[0];
  const float* state      = (const float*)d_in[1];
  const float* conv_state = (const float*)d_in[2];
  const float* W_qkv      = (const float*)d_in[3];
  const float* W_z        = (const float*)d_in[4];
  const float* W_b        = (const float*)d_in[5];
  const float* W_a        = (const float*)d_in[6];
  const float* conv_w     = (const float*)d_in[7];
  const float* A_log      = (const float*)d_in[8];
  const float* dt_bias    = (const float*)d_in[9];
  const float* norm_w     = (const float*)d_in[10];
  const float* W_out      = (const float*)d_in[11];

  float* out       = (float*)d_out;                 // 2048
  float* new_state = (float*)d_out + 2048;          // 524288
  float* new_conv  = (float*)d_out + 2048 + 524288; // 24576

  float* ws      = (float*)d_ws;
  float* mixed   = ws;          // 8192
  float* zb      = ws + 8192;   // 4096
  float* b_raw   = ws + 12288;  // 32
  float* a_raw   = ws + 12320;  // 32
  float* oflat   = ws + 12352;  // 4096
  float* scratch = ws + 16448;  // 1024

  // Deterministic host-side decision (same result on correctness call and capture).
  int maxBlk = 0;
  hipError_t qe = hipOccupancyMaxActiveBlocksPerMultiprocessor(
      &maxBlk, (const void*)k_fused, 256, 0);
  bool coop_ok = (qe == hipSuccess && maxBlk >= 4);

  if (coop_ok){
    void* args[] = {
      (void*)&x, (void*)&conv_state, (void*)&W_qkv, (void*)&W_z, (void*)&W_b,
      (void*)&W_a, (void*)&conv_w, (void*)&A_log, (void*)&dt_bias, (void*)&norm_w,
      (void*)&state, (void*)&W_out,
      (void*)&out, (void*)&new_state, (void*)&new_conv,
      (void*)&mixed, (void*)&zb, (void*)&b_raw, (void*)&a_raw, (void*)&oflat,
      (void*)&scratch
    };
    hipError_t le = hipLaunchCooperativeKernel((const void*)k_fused,
                                               dim3(1024), dim3(256),
                                               args, 0, stream);
    if (le == hipSuccess) return;
  }

  // Fallback: proven 3-kernel structure
  hipLaunchKernelGGL(k_gemv_in, dim3(1544), dim3(256), 0, stream,
                     x, W_qkv, W_z, W_b, W_a, mixed, zb, b_raw, a_raw);
  hipLaunchKernelGGL(k_head, dim3(256), dim3(256), 0, stream,
                     mixed, conv_state, conv_w, zb, b_raw, a_raw, A_log, dt_bias,
                     norm_w, state, W_out, new_state, new_conv, oflat, scratch);
  hipLaunchKernelGGL(k_gemv_out, dim3(256), dim3(256), 0, stream,
                     oflat, W_out, out);
}

// Round 7
// 177.600 us; speedup vs baseline: 1.5028x; 1.0105x over previous
//
#include <hip/hip_runtime.h>
#include <hip/hip_cooperative_groups.h>
#include <math.h>

namespace cg = cooperative_groups;

__device__ __forceinline__ float silu(float x){ return x / (1.f + expf(-x)); }

// ---------- shared: input GEMV over row-pairs (grid-stride) ----------
// rows 0..8191 -> mixed, 8192..12287 -> z, 12288..12319 -> b_raw, 12320..12351 -> a_raw
__device__ __forceinline__ void gemv_in_pairs(
    int pairIdx, int pairStride, int lane,
    const float* __restrict__ x,
    const float* __restrict__ W_qkv, const float* __restrict__ W_z,
    const float* __restrict__ W_b,   const float* __restrict__ W_a,
    float* __restrict__ mixed, float* __restrict__ zb,
    float* __restrict__ b_raw, float* __restrict__ a_raw)
{
  float4 xr[8];
  #pragma unroll
  for (int j = 0; j < 8; j++)
    xr[j] = *(const float4*)(x + j*256 + lane*4);

  for (int rp = pairIdx; rp < 6176; rp += pairStride){
    const int row0 = rp * 2;            // even; pair never straddles a segment
    const float* W; float* dst;
    if (row0 < 8192)       { W = W_qkv + (size_t)row0 * 2048;          dst = mixed + row0; }
    else if (row0 < 12288) { W = W_z   + (size_t)(row0-8192) * 2048;   dst = zb + (row0-8192); }
    else if (row0 < 12320) { W = W_b   + (size_t)(row0-12288) * 2048;  dst = b_raw + (row0-12288); }
    else                   { W = W_a   + (size_t)(row0-12320) * 2048;  dst = a_raw + (row0-12320); }

    float acc0 = 0.f, acc1 = 0.f;
    #pragma unroll
    for (int j = 0; j < 8; j++){
      float4 w0 = *(const float4*)(W + j*256 + lane*4);
      float4 w1 = *(const float4*)(W + 2048 + j*256 + lane*4);
      acc0 += w0.x*xr[j].x + w0.y*xr[j].y + w0.z*xr[j].z + w0.w*xr[j].w;
      acc1 += w1.x*xr[j].x + w1.y*xr[j].y + w1.z*xr[j].z + w1.w*xr[j].w;
    }
    #pragma unroll
    for (int off = 32; off >= 1; off >>= 1){
      acc0 += __shfl_xor(acc0, off, 64);
      acc1 += __shfl_xor(acc1, off, 64);
    }
    if (lane == 0){ dst[0] = acc0; dst[1] = acc1; }
  }
}

// ---------- shared: per-head conv+silu + state update + gated RMSnorm ----------
struct HeadSmem {
  float qn[128];
  float kn[128];
  __align__(16) float vs[128];
  float4 kvp[8][32];
  float red[4];
};

__device__ __forceinline__ void head_work(
    int h, int tid, HeadSmem& sm,
    const float* __restrict__ mixed,      const float* __restrict__ conv_state,
    const float* __restrict__ conv_w,     const float* __restrict__ zbuf,
    const float* __restrict__ b_raw,      const float* __restrict__ a_raw,
    const float* __restrict__ A_log,      const float* __restrict__ dt_bias,
    const float* __restrict__ norm_w,     const float* __restrict__ state,
    float* __restrict__ new_state, float* __restrict__ new_conv,
    float* __restrict__ out_flat)
{
  const int hb = h >> 1;
  const int t  = tid & 127;
  const int lane = tid & 63, wid = tid >> 6;

  // conv + silu (threads 0..127: q,k ; threads 128..255: v)
  float qv = 0.f, kv = 0.f;
  if (tid < 128){
    int c = hb*128 + t;
    float c0 = conv_state[c*3+0], c1 = conv_state[c*3+1], c2 = conv_state[c*3+2];
    float m  = mixed[c];
    qv = silu(c0*conv_w[c*4+0] + c1*conv_w[c*4+1] + c2*conv_w[c*4+2] + m*conv_w[c*4+3]);
    new_conv[c*3+0] = c1; new_conv[c*3+1] = c2; new_conv[c*3+2] = m;
    c = 2048 + hb*128 + t;
    c0 = conv_state[c*3+0]; c1 = conv_state[c*3+1]; c2 = conv_state[c*3+2];
    m  = mixed[c];
    kv = silu(c0*conv_w[c*4+0] + c1*conv_w[c*4+1] + c2*conv_w[c*4+2] + m*conv_w[c*4+3]);
    new_conv[c*3+0] = c1; new_conv[c*3+1] = c2; new_conv[c*3+2] = m;

    float sq = qv*qv, sk = kv*kv;
    #pragma unroll
    for (int off = 32; off >= 1; off >>= 1){
      sq += __shfl_xor(sq, off, 64);
      sk += __shfl_xor(sk, off, 64);
    }
    if (lane == 0){ sm.red[wid] = sq; sm.red[2+wid] = sk; }
  } else {
    int c = 4096 + h*128 + t;
    float c0 = conv_state[c*3+0], c1 = conv_state[c*3+1], c2 = conv_state[c*3+2];
    float m  = mixed[c];
    sm.vs[t] = silu(c0*conv_w[c*4+0] + c1*conv_w[c*4+1] + c2*conv_w[c*4+2] + m*conv_w[c*4+3]);
    new_conv[c*3+0] = c1; new_conv[c*3+1] = c2; new_conv[c*3+2] = m;
  }
  __syncthreads();
  const float qscale = rsqrtf(sm.red[0]+sm.red[1] + 1e-6f) * 0.088388347648318440550f; // 1/sqrt(128)
  const float kscale = rsqrtf(sm.red[2]+sm.red[3] + 1e-6f);
  if (tid < 128){ sm.qn[t] = qv * qscale; sm.kn[t] = kv * kscale; }
  __syncthreads();

  float g_t, beta;
  {
    const float av = a_raw[h] + dt_bias[h];
    const float sp = (av > 20.f) ? av : log1pf(expf(av));   // softplus
    g_t  = expf(-expf(A_log[h]) * sp);
    beta = 1.f / (1.f + expf(-b_raw[h]));
  }

  // state update: rows k0..k0+15, cols 4*cg..4*cg+3
  const int cg_ = tid & 31, part = tid >> 5;
  const int k0 = part * 16;
  const float* st  = state     + (size_t)h * 16384;
  float*       nst = new_state + (size_t)h * 16384;

  float4 s4[16];
  float4 kvm = make_float4(0.f, 0.f, 0.f, 0.f);
  #pragma unroll
  for (int i = 0; i < 16; i++){
    float4 sv = *(const float4*)(st + (k0+i)*128 + cg_*4);
    sv.x *= g_t; sv.y *= g_t; sv.z *= g_t; sv.w *= g_t;
    s4[i] = sv;
    const float kk = sm.kn[k0+i];
    kvm.x += sv.x*kk; kvm.y += sv.y*kk; kvm.z += sv.z*kk; kvm.w += sv.w*kk;
  }
  sm.kvp[part][cg_] = kvm;
  __syncthreads();
  float4 kt = make_float4(0.f, 0.f, 0.f, 0.f);
  #pragma unroll
  for (int p = 0; p < 8; p++){
    float4 kp = sm.kvp[p][cg_];
    kt.x += kp.x; kt.y += kp.y; kt.z += kp.z; kt.w += kp.w;
  }
  const float4 v4 = *(const float4*)(sm.vs + cg_*4);
  float4 delta;
  delta.x = (v4.x - kt.x) * beta;
  delta.y = (v4.y - kt.y) * beta;
  delta.z = (v4.z - kt.z) * beta;
  delta.w = (v4.w - kt.w) * beta;

  float4 oacc = make_float4(0.f, 0.f, 0.f, 0.f);
  #pragma unroll
  for (int i = 0; i < 16; i++){
    const float kk = sm.kn[k0+i];
    float4 ns;
    ns.x = s4[i].x + kk*delta.x;
    ns.y = s4[i].y + kk*delta.y;
    ns.z = s4[i].z + kk*delta.z;
    ns.w = s4[i].w + kk*delta.w;
    *(float4*)(nst + (k0+i)*128 + cg_*4) = ns;
    const float qq = sm.qn[k0+i];
    oacc.x += ns.x*qq; oacc.y += ns.y*qq; oacc.z += ns.z*qq; oacc.w += ns.w*qq;
  }
  __syncthreads();           // kvp reuse
  sm.kvp[part][cg_] = oacc;
  __syncthreads();
  if (part == 0){
    float4 o = make_float4(0.f, 0.f, 0.f, 0.f);
    #pragma unroll
    for (int p = 0; p < 8; p++){
      float4 op = sm.kvp[p][cg_];
      o.x += op.x; o.y += op.y; o.z += op.z; o.w += op.w;
    }
    const float4 z4 = *(const float4*)(zbuf + h*128 + cg_*4);
    float4 g4;
    g4.x = o.x * silu(z4.x);
    g4.y = o.y * silu(z4.y);
    g4.z = o.z * silu(z4.z);
    g4.w = o.w * silu(z4.w);
    float s2 = g4.x*g4.x + g4.y*g4.y + g4.z*g4.z + g4.w*g4.w;
    #pragma unroll
    for (int off = 16; off >= 1; off >>= 1) s2 += __shfl_xor(s2, off, 64);
    const float r = rsqrtf(s2 * (1.f/128.f) + 1e-6f);
    const float4 nw = *(const float4*)(norm_w + cg_*4);
    float4 ov;
    ov.x = g4.x * r * nw.x;
    ov.y = g4.y * r * nw.y;
    ov.z = g4.z * r * nw.z;
    ov.w = g4.w * r * nw.w;
    *(float4*)(out_flat + h*128 + cg_*4) = ov;
  }
}

// ================= Fused cooperative kernel: 1024 blocks x 256 thr =================
// __launch_bounds__(256,4): 4 waves/EU = 16 waves/CU = 4 blocks/CU co-resident
// (required: cooperative launch of 1024 blocks on 256 CUs).
// Phase B loads each block's 2 W_out rows into 32 VGPRs/lane; they survive
// grid.sync so phase C never touches W_out memory again.
__global__ __launch_bounds__(256, 4) void k_fused(
    const float* __restrict__ x,
    const float* __restrict__ conv_state,
    const float* __restrict__ W_qkv,
    const float* __restrict__ W_z,
    const float* __restrict__ W_b,
    const float* __restrict__ W_a,
    const float* __restrict__ conv_w,
    const float* __restrict__ A_log,
    const float* __restrict__ dt_bias,
    const float* __restrict__ norm_w,
    const float* __restrict__ state,
    const float* __restrict__ Wout,
    float* __restrict__ out,
    float* __restrict__ new_state,
    float* __restrict__ new_conv,
    float* __restrict__ mixed,
    float* __restrict__ zb,
    float* __restrict__ b_raw,
    float* __restrict__ a_raw,
    float* __restrict__ oflat)
{
  cg::grid_group grid = cg::this_grid();
  const int b    = blockIdx.x;
  const int tid  = threadIdx.x;
  const int lane = tid & 63;
  const int wave = tid >> 6;

  __shared__ HeadSmem sm;
  __shared__ float redC[4];

  // ---- Phase A: input GEMVs, 6176 row-pairs over 4096 waves ----
  gemv_in_pairs(b*4 + wave, 4096, lane, x, W_qkv, W_z, W_b, W_a,
                mixed, zb, b_raw, a_raw);

  grid.sync();

  // ---- Phase B: head update (blocks 0..31) + W_out -> registers (all blocks) ----
  // This wave owns half a W_out row: row = 2b + (wave>>1), half = wave&1.
  const int rowC = b*2 + (wave >> 1);
  const int half = wave & 1;
  const float* Wr = Wout + (size_t)rowC * 4096 + half * 2048;

  float4 wreg[8];
  if (b < 32){
    head_work(b, tid, sm, mixed, conv_state, conv_w, zb, b_raw, a_raw,
              A_log, dt_bias, norm_w, state, new_state, new_conv, oflat);
    #pragma unroll
    for (int j = 0; j < 8; j++)
      wreg[j] = *(const float4*)(Wr + j*256 + lane*4);
  } else {
    #pragma unroll
    for (int j = 0; j < 8; j++)
      wreg[j] = *(const float4*)(Wr + j*256 + lane*4);
  }

  grid.sync();

  // ---- Phase C: dot register-resident W rows against oflat (L2-hot, 16 KB) ----
  {
    const float* xh = oflat + half * 2048;
    float acc = 0.f;
    #pragma unroll
    for (int j = 0; j < 8; j++){
      float4 xv = *(const float4*)(xh + j*256 + lane*4);
      acc += wreg[j].x*xv.x + wreg[j].y*xv.y + wreg[j].z*xv.z + wreg[j].w*xv.w;
    }
    #pragma unroll
    for (int off = 32; off >= 1; off >>= 1) acc += __shfl_xor(acc, off, 64);
    if (lane == 0) redC[wave] = acc;
    __syncthreads();
    if (tid < 2) out[b*2 + tid] = redC[2*tid] + redC[2*tid+1];
  }
}

// ================= Fallback path (R4 3-kernel structure) =================
__global__ __launch_bounds__(256) void k_gemv_in(
    const float* __restrict__ x,
    const float* __restrict__ W_qkv, const float* __restrict__ W_z,
    const float* __restrict__ W_b,   const float* __restrict__ W_a,
    float* __restrict__ mixed, float* __restrict__ zb,
    float* __restrict__ b_raw, float* __restrict__ a_raw)
{
  const int lane = threadIdx.x & 63, wave = threadIdx.x >> 6;
  gemv_in_pairs(blockIdx.x*4 + wave, 6176, lane, x, W_qkv, W_z, W_b, W_a,
                mixed, zb, b_raw, a_raw);
}

__global__ __launch_bounds__(256) void k_head(
    const float* __restrict__ mixed,      const float* __restrict__ conv_state,
    const float* __restrict__ conv_w,     const float* __restrict__ zbuf,
    const float* __restrict__ b_raw,      const float* __restrict__ a_raw,
    const float* __restrict__ A_log,      const float* __restrict__ dt_bias,
    const float* __restrict__ norm_w,     const float* __restrict__ state,
    const float* __restrict__ Wout,
    float* __restrict__ new_state, float* __restrict__ new_conv,
    float* __restrict__ out_flat,  float* __restrict__ scratch)
{
  const int b = blockIdx.x, tid = threadIdx.x;
  if (b >= 32){
    const float4* W4 = (const float4*)Wout + (size_t)b * 8192;
    float4 a = make_float4(0.f, 0.f, 0.f, 0.f);
    #pragma unroll
    for (int j = 0; j < 32; j++){
      float4 w = W4[j*256 + tid];
      a.x += w.x; a.y += w.y; a.z += w.z; a.w += w.w;
    }
    if (tid == 0) scratch[b] = a.x + a.y + a.z + a.w;
    return;
  }
  __shared__ HeadSmem sm;
  head_work(b, tid, sm, mixed, conv_state, conv_w, zbuf, b_raw, a_raw,
            A_log, dt_bias, norm_w, state, new_state, new_conv, out_flat);
}

__global__ __launch_bounds__(256) void k_gemv_out(
    const float* __restrict__ out_flat,
    const float* __restrict__ Wout,
    float* __restrict__ out)
{
  __shared__ __align__(16) float xs[4096];
  const int tid = threadIdx.x;
  #pragma unroll
  for (int i = 0; i < 4; i++)
    *(float4*)(xs + tid*4 + i*1024) = *(const float4*)(out_flat + tid*4 + i*1024);
  __syncthreads();

  const int lane = tid & 63, wave = tid >> 6;
  const int row0 = blockIdx.x * 8 + wave * 2;
  const float* W0 = Wout + (size_t)row0 * 4096;
  float acc0 = 0.f, acc1 = 0.f;
  #pragma unroll
  for (int j = 0; j < 16; j++){
    float4 w0 = *(const float4*)(W0 + j*256 + lane*4);
    float4 w1 = *(const float4*)(W0 + 4096 + j*256 + lane*4);
    const float x0 = xs[j*256+lane*4+0], x1 = xs[j*256+lane*4+1];
    const float x2 = xs[j*256+lane*4+2], x3 = xs[j*256+lane*4+3];
    acc0 += w0.x*x0 + w0.y*x1 + w0.z*x2 + w0.w*x3;
    acc1 += w1.x*x0 + w1.y*x1 + w1.z*x2 + w1.w*x3;
  }
  #pragma unroll
  for (int off = 32; off >= 1; off >>= 1){
    acc0 += __shfl_xor(acc0, off, 64);
    acc1 += __shfl_xor(acc1, off, 64);
  }
  if (lane == 0){ out[row0] = acc0; out[row0+1] = acc1; }
}

extern "C" void kernel_launch(void* const* d_in, const int* in_sizes, int n_in,
                              void* d_out, int out_size, void* d_ws, size_t ws_size,
                              hipStream_t stream) {
  const float* x          = (const float*)d_in[0];
  const float* state      = (const float*)d_in[1];
  const float* conv_state = (const float*)d_in[2];
  const float* W_qkv      = (const float*)d_in[3];
  const float* W_z        = (const float*)d_in[4];
  const float* W_b        = (const float*)d_in[5];
  const float* W_a        = (const float*)d_in[6];
  const float* conv_w     = (const float*)d_in[7];
  const float* A_log      = (const float*)d_in[8];
  const float* dt_bias    = (const float*)d_in[9];
  const float* norm_w     = (const float*)d_in[10];
  const float* W_out      = (const float*)d_in[11];

  float* out       = (float*)d_out;                 // 2048
  float* new_state = (float*)d_out + 2048;          // 524288
  float* new_conv  = (float*)d_out + 2048 + 524288; // 24576

  float* ws      = (float*)d_ws;
  float* mixed   = ws;          // 8192
  float* zb      = ws + 8192;   // 4096
  float* b_raw   = ws + 12288;  // 32
  float* a_raw   = ws + 12320;  // 32
  float* oflat   = ws + 12352;  // 4096
  float* scratch = ws + 16448;  // 1024 (fallback prefetch sink)

  // Deterministic host-side decision (same result on correctness call and capture).
  int maxBlk = 0;
  hipError_t qe = hipOccupancyMaxActiveBlocksPerMultiprocessor(
      &maxBlk, (const void*)k_fused, 256, 0);
  bool coop_ok = (qe == hipSuccess && maxBlk >= 4);

  if (coop_ok){
    void* args[] = {
      (void*)&x, (void*)&conv_state, (void*)&W_qkv, (void*)&W_z, (void*)&W_b,
      (void*)&W_a, (void*)&conv_w, (void*)&A_log, (void*)&dt_bias, (void*)&norm_w,
      (void*)&state, (void*)&W_out,
      (void*)&out, (void*)&new_state, (void*)&new_conv,
      (void*)&mixed, (void*)&zb, (void*)&b_raw, (void*)&a_raw, (void*)&oflat
    };
    hipError_t le = hipLaunchCooperativeKernel((const void*)k_fused,
                                               dim3(1024), dim3(256),
                                               args, 0, stream);
    if (le == hipSuccess) return;
  }

  // Fallback: proven 3-kernel structure
  hipLaunchKernelGGL(k_gemv_in, dim3(1544), dim3(256), 0, stream,
                     x, W_qkv, W_z, W_b, W_a, mixed, zb, b_raw, a_raw);
  hipLaunchKernelGGL(k_head, dim3(256), dim3(256), 0, stream,
                     mixed, conv_state, conv_w, zb, b_raw, a_raw, A_log, dt_bias,
                     norm_w, state, W_out, new_state, new_conv, oflat, scratch);
  hipLaunchKernelGGL(k_gemv_out, dim3(256), dim3(256), 0, stream,
                     oflat, W_out, out);
}